// Round 9
// baseline (310.958 us; speedup 1.0000x reference)
//
#include <hip/hip_runtime.h>

#define BATCH  16
#define NPRED  25200
#define NCLS   80
#define CDIM   85
#define TOPK   4096
#define NBUCK  4096
#define MAXDET 1000
#define CONF_T 0.25f
#define IOU_T  0.45f
#define MAXWH  7680.0f
#define ORD_BASE 0xBE800000u   // ord(0.25f); valid score s>0.25 <=> ord > ORD_BASE

typedef unsigned long long u64;
typedef unsigned int u32;
typedef unsigned short u16;
typedef unsigned char u8;

__device__ __forceinline__ u64 umax64(u64 a, u64 b) { return a > b ? a : b; }
__device__ __forceinline__ u64 umin64(u64 a, u64 b) { return a < b ? a : b; }

__device__ __forceinline__ void cx_u64(u64* a, int i, int p, bool desc) {
    u64 x = a[i], y = a[p];
    if (desc ? (x < y) : (x > y)) { a[i] = y; a[p] = x; }
}

// ---------------- hybrid bitonic sort: 1024 threads × 4 regs, LDS only for j>=256 ----

__device__ void hybrid_sort4096_desc(u64 r[4], u64* a) {
    const int tid = threadIdx.x;
    for (int k = 2; k <= 4096; k <<= 1) {
        if (k >= 512) {                      // LDS stages: j = min(k/2,2048) .. 256
            int jmax = (k >> 1) > 2048 ? 2048 : (k >> 1);
#pragma unroll
            for (int e = 0; e < 4; ++e) a[4 * tid + e] = r[e];
            __syncthreads();
            for (int j = jmax; j >= 256; j >>= 1) {
#pragma unroll
                for (int t2 = 0; t2 < 2; ++t2) {
                    int q = (t2 << 10) | tid;
                    int i = ((q & ~(j - 1)) << 1) | (q & (j - 1));
                    cx_u64(a, i, i | j, (i & k) == 0);
                }
                __syncthreads();
            }
#pragma unroll
            for (int e = 0; e < 4; ++e) r[e] = a[4 * tid + e];
            __syncthreads();
        }
        {                                    // shuffle stages: j = min(k/2,128) .. 4
            int jstart = (k >> 1) > 128 ? 128 : (k >> 1);
            bool desc = (((4 * tid) & k) == 0);
            for (int j = jstart; j >= 4; j >>= 1) {
                int m = j >> 2;
                bool take_max = (((tid & m) == 0) == desc);
#pragma unroll
                for (int e = 0; e < 4; ++e) {
                    u64 v = __shfl_xor(r[e], m, 64);
                    r[e] = take_max ? umax64(r[e], v) : umin64(r[e], v);
                }
            }
        }
        if (k >= 4) {                        // j=2
            bool desc = (((4 * tid) & k) == 0);
            u64 x0 = r[0], x2 = r[2];
            r[0] = desc ? umax64(x0, x2) : umin64(x0, x2);
            r[2] = desc ? umin64(x0, x2) : umax64(x0, x2);
            u64 x1 = r[1], x3 = r[3];
            r[1] = desc ? umax64(x1, x3) : umin64(x1, x3);
            r[3] = desc ? umin64(x1, x3) : umax64(x1, x3);
        }
        {                                    // j=1
            bool d01 = (((4 * tid + 0) & k) == 0);
            bool d23 = (((4 * tid + 2) & k) == 0);
            u64 x0 = r[0], x1 = r[1];
            r[0] = d01 ? umax64(x0, x1) : umin64(x0, x1);
            r[1] = d01 ? umin64(x0, x1) : umax64(x0, x1);
            u64 x2 = r[2], x3 = r[3];
            r[2] = d23 ? umax64(x2, x3) : umin64(x2, x3);
            r[3] = d23 ? umin64(x2, x3) : umax64(x2, x3);
        }
    }
}

// full desc sort of 256 u64 held in wave 0 (4 regs/lane), zero barriers
__device__ void wave_sort256_desc(u64 r[4]) {
    const int lane = threadIdx.x & 63;
    for (int k = 2; k <= 256; k <<= 1) {
        int jstart = (k >> 1) > 128 ? 128 : (k >> 1);
        bool desc = (((4 * lane) & k) == 0);
        for (int j = jstart; j >= 4; j >>= 1) {
            int m = j >> 2;
            bool take_max = (((lane & m) == 0) == desc);
#pragma unroll
            for (int e = 0; e < 4; ++e) {
                u64 v = __shfl_xor(r[e], m, 64);
                r[e] = take_max ? umax64(r[e], v) : umin64(r[e], v);
            }
        }
        if (k >= 4) {
            u64 x0 = r[0], x2 = r[2];
            r[0] = desc ? umax64(x0, x2) : umin64(x0, x2);
            r[2] = desc ? umin64(x0, x2) : umax64(x0, x2);
            u64 x1 = r[1], x3 = r[3];
            r[1] = desc ? umax64(x1, x3) : umin64(x1, x3);
            r[3] = desc ? umin64(x1, x3) : umax64(x1, x3);
        }
        {
            bool d01 = (((4 * lane + 0) & k) == 0);
            bool d23 = (((4 * lane + 2) & k) == 0);
            u64 x0 = r[0], x1 = r[1];
            r[0] = d01 ? umax64(x0, x1) : umin64(x0, x1);
            r[1] = d01 ? umin64(x0, x1) : umax64(x0, x1);
            u64 x2 = r[2], x3 = r[3];
            r[2] = d23 ? umax64(x2, x3) : umin64(x2, x3);
            r[3] = d23 ? umin64(x2, x3) : umax64(x2, x3);
        }
    }
}

// ---------------- K1: score / argmax / key / histogram ----------------
// key = ord(score)<<32 | (32767-n)<<7 | cls   (desc sort == stable argsort(-s))

__global__ __launch_bounds__(256) void k1_score(const float* __restrict__ pred,
                                                u64* __restrict__ keys,
                                                u32* __restrict__ ghist) {
    const int lane = threadIdx.x & 63;
    const int l16 = lane & 15;
    const long long gw = (long long)blockIdx.x * 4 + (threadIdx.x >> 6);
    const long long rowIdx = gw * 4 + (lane >> 4);       // global row in [0, BATCH*NPRED)
    const float* row = pred + rowIdx * CDIM;
    float obj = row[4];
    // classes 0..63: 4 consecutive floats per lane (compiler merges to dwordx4)
    float v0 = row[5 + 4 * l16 + 0];
    float v1 = row[5 + 4 * l16 + 1];
    float v2 = row[5 + 4 * l16 + 2];
    float v3 = row[5 + 4 * l16 + 3];
    float v4 = row[69 + l16];                            // classes 64..79
    u64 m = 0ull;
    {
        int c = 4 * l16;
        float s0 = v0 * obj;                             // reference order: product then max
        u64 mk = ((u64)(__float_as_uint(s0) | 0x80000000u) << 32) | (u64)(u32)(NCLS - 1 - c);
        m = mk;
        float s1 = v1 * obj;
        mk = ((u64)(__float_as_uint(s1) | 0x80000000u) << 32) | (u64)(u32)(NCLS - 1 - (c + 1));
        if (mk > m) m = mk;
        float s2 = v2 * obj;
        mk = ((u64)(__float_as_uint(s2) | 0x80000000u) << 32) | (u64)(u32)(NCLS - 1 - (c + 2));
        if (mk > m) m = mk;
        float s3 = v3 * obj;
        mk = ((u64)(__float_as_uint(s3) | 0x80000000u) << 32) | (u64)(u32)(NCLS - 1 - (c + 3));
        if (mk > m) m = mk;
        float s4 = v4 * obj;
        mk = ((u64)(__float_as_uint(s4) | 0x80000000u) << 32) | (u64)(u32)(NCLS - 1 - (64 + l16));
        if (mk > m) m = mk;
    }
#pragma unroll
    for (int o = 8; o > 0; o >>= 1) {
        u64 other = __shfl_xor(m, o, 64);                // reduce within 16-lane group
        if (other > m) m = other;
    }
    if (l16 == 0) {
        const int b = (int)(rowIdx / NPRED);
        const int n = (int)(rowIdx - (long long)b * NPRED);
        float best = __uint_as_float((u32)(m >> 32) & 0x7FFFFFFFu);
        float s = (best > CONF_T) ? best : -1.0f;
        u32 u = __float_as_uint(s);
        u32 ord = (u & 0x80000000u) ? ~u : (u | 0x80000000u);
        keys[rowIdx] = ((u64)ord << 32) | ((u64)(u32)(32767 - n) << 7) |
                       (u64)(u32)((NCLS - 1) - (int)(m & 0x7Fu));
        if (ord > ORD_BASE)
            atomicAdd(&ghist[b * NBUCK + ((ord - ORD_BASE - 1u) >> 12)], 1u);
    }
}

// ---------------- K2t: per-batch threshold {T, C1, R} from histogram ----------------

__global__ __launch_bounds__(1024) void k2t(const u32* __restrict__ ghist,
                                            int* __restrict__ tcr,
                                            u32* __restrict__ count) {
    __shared__ u32 wsum[16];
    __shared__ int sh_T, sh_C1, sh_R;
    const int b = blockIdx.x;
    const int tid = threadIdx.x;
    const int lane = tid & 63;
    const int wid = tid >> 6;
    u32 h[4];
    u32 tsum = 0;
#pragma unroll
    for (int e = 0; e < 4; ++e) {
        h[e] = ghist[b * NBUCK + (NBUCK - 1 - (4 * tid + e))];   // descending bucket order
        tsum += h[e];
    }
    u32 inc = tsum;
    for (int o = 1; o < 64; o <<= 1) {
        u32 v = __shfl_up(inc, o, 64);
        if (lane >= o) inc += v;
    }
    if (lane == 63) wsum[wid] = inc;
    __syncthreads();
    if (tid == 0) {
        u32 run = 0;
        for (int i = 0; i < 16; ++i) { u32 t = wsum[i]; wsum[i] = run; run += t; }
        sh_T = -1; sh_C1 = (int)run; sh_R = 0;           // defaults: < 4096 valid total
    }
    __syncthreads();
    {
        u32 cum = wsum[wid] + (inc - tsum);              // exclusive prefix before this thread
#pragma unroll
        for (int e = 0; e < 4; ++e) {
            if (h[e] > 0 && cum < (u32)TOPK && cum + h[e] >= (u32)TOPK) {
                sh_T = NBUCK - 1 - (4 * tid + e);        // unique crossing
                sh_C1 = (int)cum;
                sh_R = TOPK - (int)cum;
            }
            cum += h[e];
        }
    }
    __syncthreads();
    if (tid == 0) {
        tcr[b * 8 + 0] = sh_T;
        tcr[b * 8 + 1] = sh_C1;
        tcr[b * 8 + 2] = sh_R;
        tcr[b * 8 + 3] = 0;                              // c1pos
        tcr[b * 8 + 4] = 0;                              // sidepos
    }
    if (tid < NCLS) count[b * NCLS + tid] = 0u;
}

// ---------------- K2c: parallel compaction (16×25 blocks) ----------------

__global__ __launch_bounds__(1024) void k2c(const u64* __restrict__ keys,
                                            int* __restrict__ tcr,
                                            u64* __restrict__ topBuf,
                                            u64* __restrict__ sideBuf) {
    const int b = blockIdx.x;
    if (threadIdx.x >= 1008) return;                     // 25 * 1008 == NPRED
    const int n = blockIdx.y * 1008 + threadIdx.x;
    const int T = tcr[b * 8 + 0];
    u64 key = keys[(long long)b * NPRED + n];
    u32 hi = (u32)(key >> 32);
    if (hi > ORD_BASE) {
        int bt = (int)((hi - ORD_BASE - 1u) >> 12);
        if (bt > T) {
            int slot = atomicAdd(&tcr[b * 8 + 3], 1);    // device-scope; order irrelevant
            topBuf[b * 4096 + slot] = key;               // slot < C1 <= 4095
        } else if (bt == T) {
            int s2 = atomicAdd(&tcr[b * 8 + 4], 1);
            if (s2 < 1024) sideBuf[b * 1024 + s2] = key; // >1024 in one bucket: implausible
        }
    }
}

// ---------------- K2s: bucket-T select + full sort -> sorted top-4096 ----------------

__global__ __launch_bounds__(1024) void k2s(const int* __restrict__ tcr,
                                            const u64* __restrict__ topBuf,
                                            const u64* __restrict__ sideBuf,
                                            u64* __restrict__ topSorted) {
    __shared__ u64 arena[4096];
    __shared__ u64 side[1024];
    const int b = blockIdx.x;
    const int tid = threadIdx.x;
    const int lane = tid & 63;
    const int wid = tid >> 6;
    const int C1 = tcr[b * 8 + 1];
    const int R = tcr[b * 8 + 2];
    int cntT = tcr[b * 8 + 4];
    if (cntT > 1024) cntT = 1024;
#pragma unroll
    for (int e = 0; e < 4; ++e) {
        int i = e * 1024 + tid;                          // coalesced
        arena[i] = (i < C1) ? topBuf[b * 4096 + i] : 0ull;
    }
    side[tid] = (tid < cntT) ? sideBuf[b * 1024 + tid] : 0ull;
    __syncthreads();

    if (R > 0) {
        if (cntT <= 256) {
            if (wid == 0) {                              // single-wave in-register sort
                u64 r[4];
#pragma unroll
                for (int e = 0; e < 4; ++e) r[e] = side[4 * lane + e];
                wave_sort256_desc(r);
#pragma unroll
                for (int e = 0; e < 4; ++e) side[4 * lane + e] = r[e];
            }
        } else {                                         // rare fallback: block bitonic 1024
            for (int k = 2; k <= 1024; k <<= 1) {
                for (int j = k >> 1; j >= 1; j >>= 1) {
                    if (tid < 512) {
                        int q = tid;
                        int i = ((q & ~(j - 1)) << 1) | (q & (j - 1));
                        cx_u64(side, i, i | j, (i & k) == 0);
                    }
                    __syncthreads();
                }
            }
        }
        __syncthreads();
        if (tid < R) arena[C1 + tid] = side[tid];        // R <= cntT
    }
    __syncthreads();

    u64 r[4];
#pragma unroll
    for (int e = 0; e < 4; ++e) r[e] = arena[4 * tid + e];
    hybrid_sort4096_desc(r, arena);
#pragma unroll
    for (int e = 0; e < 4; ++e) topSorted[(long long)b * TOPK + 4 * tid + e] = r[e];
}

// ---------------- K3a: per-entry class byte + offset-box + class counts + zero flags ----

__global__ __launch_bounds__(256) void k3a_build(const float* __restrict__ pred,
                                                 const u64* __restrict__ topSorted,
                                                 float4* __restrict__ ob,
                                                 u8* __restrict__ clsb,
                                                 u32* __restrict__ count,
                                                 u8* __restrict__ keep,
                                                 u8* __restrict__ gsupp) {
    const int idx = blockIdx.x * 256 + threadIdx.x;      // 0 .. BATCH*TOPK-1
    const int b = idx >> 12;
    u64 key = topSorted[idx];
    u32 hi = (u32)(key >> 32);
    u8 c = 0xFF;
    if (hi > 0x80000000u) {                              // score > 0 (valid)
        int n = 32767 - (int)((key >> 7) & 0x7FFFu);
        int ci = (int)(key & 0x7Fu);
        const float* row = pred + ((long long)b * NPRED + n) * CDIM;
        float x = row[0], y = row[1], w = row[2], h = row[3];
        float off = (float)ci * MAXWH;
        float4 o;
        o.x = (x - w * 0.5f) + off;
        o.y = (y - h * 0.5f) + off;
        o.z = (x + w * 0.5f) + off;
        o.w = (y + h * 0.5f) + off;
        ob[idx] = o;
        c = (u8)ci;
        atomicAdd(&count[b * NCLS + ci], 1u);
    }
    clsb[idx] = c;
    keep[idx] = 0;
    gsupp[idx] = 0;
}

// ---------------- K3g: stable per-class index gather (one wave per (b,c)) ----------------

__global__ __launch_bounds__(64) void k3g_gather(const u8* __restrict__ clsb,
                                                 const u32* __restrict__ count,
                                                 u32* __restrict__ startg,
                                                 u16* __restrict__ segIdx) {
    const int b = blockIdx.x;
    const int c = blockIdx.y;
    const int lane = threadIdx.x;
    // start = sum_{c' < c} count[b][c']  (NCLS=80 > 64: two chunks)
    u32 s = (lane < c) ? count[b * NCLS + lane] : 0u;
    if (lane + 64 < c) s += count[b * NCLS + 64 + lane];
#pragma unroll
    for (int o = 32; o > 0; o >>= 1) s += __shfl_xor(s, o, 64);
    if (lane == 0) startg[b * NCLS + c] = s;
    const u32 base = (u32)b * 4096u;
    u32 pos = s;
    const u64 lt = (1ull << lane) - 1ull;
    for (int it = 0; it < 64; ++it) {
        u8 cc = clsb[base + it * 64 + lane];
        u64 m = __ballot(cc == (u8)c);
        if (cc == (u8)c) {
            int ofs = __popcll(m & lt);
            segIdx[base + pos + ofs] = (u16)(it * 64 + lane);
        }
        pos += (u32)__popcll(m);
    }
}

// ---------------- K3n: greedy NMS, one wave per (b,c) ----------------

__global__ __launch_bounds__(64) void k3n_nms(const float4* __restrict__ ob,
                                              const u16* __restrict__ segIdx,
                                              const u32* __restrict__ count,
                                              const u32* __restrict__ startg,
                                              u8* __restrict__ keep,
                                              u8* gsupp_) {
    const int b = blockIdx.x;
    const int c = blockIdx.y;
    const int lane = threadIdx.x;
    const int n = (int)count[b * NCLS + c];
    if (n == 0) return;
    const u32 base = startg[b * NCLS + c];
    __shared__ float4 sbox[1024];
    __shared__ u16 sidx[1024];
    __shared__ u8 ssupp_[1024];
    volatile u8* ssupp = ssupp_;
    volatile u8* gsupp = gsupp_ + b * 4096 + base;       // fallback (n > 1024), pre-zeroed
    const float4* obb = ob + b * 4096;
    const u16* seg = segIdx + b * 4096 + base;

    for (int j = lane; j < n && j < 1024; j += 64) {
        int r = seg[j];
        sidx[j] = (u16)r;
        sbox[j] = obb[r];
        ssupp_[j] = 0;
    }
    __syncthreads();

    {
#pragma clang fp contract(off)
        for (int ii = 0; ii < n; ++ii) {
            bool sup = (ii < 1024) ? (ssupp[ii] != 0) : (gsupp[ii] != 0);
            if (sup) continue;                           // wave-uniform
            int ri = (ii < 1024) ? (int)sidx[ii] : (int)seg[ii];
            if (lane == 0) keep[b * 4096 + ri] = 1;
            float4 bi = (ii < 1024) ? sbox[ii] : obb[seg[ii]];
            float a1 = (bi.z - bi.x) * (bi.w - bi.y);
            for (int jj = ii + 1 + lane; jj < n; jj += 64) {
                float4 bj = (jj < 1024) ? sbox[jj] : obb[seg[jj]];
                float ltx = fmaxf(bi.x, bj.x);
                float lty = fmaxf(bi.y, bj.y);
                float rbx = fminf(bi.z, bj.z);
                float rby = fminf(bi.w, bj.w);
                float ww = fmaxf(rbx - ltx, 0.0f);
                float hh = fmaxf(rby - lty, 0.0f);
                float inter = ww * hh;
                float a2 = (bj.z - bj.x) * (bj.w - bj.y);
                float iou = inter / (((a1 + a2) - inter) + 1e-7f);
                if (iou > IOU_T) {
                    if (jj < 1024) ssupp[jj] = 1; else gsupp[jj] = 1;
                }
            }
            __syncthreads();                             // single-wave: orders LDS supp writes
        }
    }
}

// ---------------- K3o: rank-order compaction + output ----------------

__global__ __launch_bounds__(256) void k3o_out(const float* __restrict__ pred,
                                               const u64* __restrict__ topSorted,
                                               const u8* __restrict__ keep,
                                               float* __restrict__ out) {
    const int b = blockIdx.x;
    const int tid = threadIdx.x;
    __shared__ u64 words[64];
    __shared__ int wpre[64];
    float* outb = out + (long long)b * MAXDET * 6;
    for (int i = tid; i < MAXDET * 6; i += 256) outb[i] = 0.0f;   // d_out is poisoned
    const u8* kp = keep + b * 4096;
    if (tid < 64) {
        u64 w = 0ull;
        const u64* k8 = (const u64*)(kp + tid * 64);
#pragma unroll
        for (int q = 0; q < 8; ++q) {
            u64 v = k8[q];
#pragma unroll
            for (int bb = 0; bb < 8; ++bb)
                if ((v >> (8 * bb)) & 0xFFull) w |= 1ull << (q * 8 + bb);
        }
        words[tid] = w;
    }
    __syncthreads();
    if (tid == 0) {
        int run = 0;
        for (int t = 0; t < 64; ++t) { wpre[t] = run; run += __popcll(words[t]); }
    }
    __syncthreads();
    const u64* kb = topSorted + (long long)b * TOPK;
    for (int r = tid; r < 4096; r += 256) {
        int wd = r >> 6;
        if ((words[wd] >> (r & 63)) & 1ull) {
            int pos = wpre[wd] + __popcll(words[wd] & ((1ull << (r & 63)) - 1ull));
            if (pos < MAXDET) {
                u64 key = kb[r];
                u32 hi = (u32)(key >> 32);
                int n = 32767 - (int)((key >> 7) & 0x7FFFu);
                const float* row = pred + ((long long)b * NPRED + n) * CDIM;
                float x = row[0], y = row[1], w2 = row[2], h = row[3];
                float* o = outb + pos * 6;
                o[0] = x - w2 * 0.5f;
                o[1] = y - h * 0.5f;
                o[2] = x + w2 * 0.5f;
                o[3] = y + h * 0.5f;
                o[4] = __uint_as_float(hi & 0x7FFFFFFFu);   // score
                o[5] = (float)(key & 0x7Fu);                // class (as float)
            }
        }
    }
}

// ---------------- launch ----------------

extern "C" void kernel_launch(void* const* d_in, const int* in_sizes, int n_in,
                              void* d_out, int out_size, void* d_ws, size_t ws_size,
                              hipStream_t stream) {
    const float* pred = (const float*)d_in[0];
    float* out = (float*)d_out;

    char* ws = (char*)d_ws;
    u64* keys      = (u64*)ws;                            // 16*25200*8 = 3,225,600 B
    u64* topSorted = (u64*)(ws + 3225600);                //   524,288 B
    float4* ob     = (float4*)(ws + 3749888);             // 1,048,576 B
    u8* clsb       = (u8*)(ws + 4798464);                 //    65,536 B
    u16* segIdx    = (u16*)(ws + 4864000);                //   131,072 B
    u32* startg    = (u32*)(ws + 4995072);                //     5,120 B
    u32* count     = (u32*)(ws + 5000192);                //     5,120 B  [zeroed by k2t]
    u8* keep       = (u8*)(ws + 5005312);                 //    65,536 B  [zeroed by k3a]
    u8* gsupp      = (u8*)(ws + 5070848);                 //    65,536 B  [zeroed by k3a]
    u64* topBuf    = (u64*)(ws + 5136384);                //   524,288 B
    u64* sideBuf   = (u64*)(ws + 5660672);                //   131,072 B
    u32* ghist     = (u32*)(ws + 5791744);                //   262,144 B  [memset]
    int* tcr       = (int*)(ws + 6053888);                //       512 B  [written by k2t]
    (void)hipMemsetAsync(ws + 5791744, 0, 262144, stream);

    hipLaunchKernelGGL(k1_score, dim3(BATCH * NPRED / 16), dim3(256), 0, stream,
                       pred, keys, ghist);
    hipLaunchKernelGGL(k2t, dim3(BATCH), dim3(1024), 0, stream, ghist, tcr, count);
    hipLaunchKernelGGL(k2c, dim3(BATCH, 25), dim3(1024), 0, stream,
                       keys, tcr, topBuf, sideBuf);
    hipLaunchKernelGGL(k2s, dim3(BATCH), dim3(1024), 0, stream,
                       tcr, topBuf, sideBuf, topSorted);
    hipLaunchKernelGGL(k3a_build, dim3(BATCH * TOPK / 256), dim3(256), 0, stream,
                       pred, topSorted, ob, clsb, count, keep, gsupp);
    hipLaunchKernelGGL(k3g_gather, dim3(BATCH, NCLS), dim3(64), 0, stream,
                       clsb, count, startg, segIdx);
    hipLaunchKernelGGL(k3n_nms, dim3(BATCH, NCLS), dim3(64), 0, stream,
                       ob, segIdx, count, startg, keep, gsupp);
    hipLaunchKernelGGL(k3o_out, dim3(BATCH), dim3(256), 0, stream, pred, topSorted, keep, out);
}